// Round 13
// baseline (1147.697 us; speedup 1.0000x reference)
//
#include <hip/hip_runtime.h>
#include <stdint.h>

#define NTOK 16384
#define HD   2048
#define ID   768
#define TOPK 8

typedef __bf16 bf16x8 __attribute__((ext_vector_type(8)));
typedef float  floatx4 __attribute__((ext_vector_type(4)));
typedef unsigned short ushort8 __attribute__((ext_vector_type(8)));

__device__ __forceinline__ unsigned short f32_to_bf16_rne(float f) {
    union { float f; uint32_t u; } v; v.f = f;
    uint32_t u = v.u;
    u += 0x7FFFu + ((u >> 16) & 1u);
    return (unsigned short)(u >> 16);
}

// async global->LDS, 16B/lane; LDS dest is wave-uniform base (HW adds lane*16)
#define GLD_LDS(gsrc, ldst)                                                              \
    __builtin_amdgcn_global_load_lds(                                                    \
        (const __attribute__((address_space(1))) uint32_t*)(const void*)(gsrc),          \
        (__attribute__((address_space(3))) uint32_t*)(void*)(ldst), 16, 0, 0)

template<int VM> __device__ __forceinline__ void wait_vm() {
    if constexpr (VM == 8)      asm volatile("s_waitcnt vmcnt(8)" ::: "memory");
    else if constexpr (VM == 3) asm volatile("s_waitcnt vmcnt(3)" ::: "memory");
    else                        asm volatile("s_waitcnt vmcnt(0)" ::: "memory");
}
#define BARRIER() do { asm volatile("" ::: "memory");              \
                       __builtin_amdgcn_s_barrier();               \
                       asm volatile("" ::: "memory"); } while (0)

// ================= PREP: convert_hs | convert_w3 | compute_w, one dispatch =====
#define NB_HS (NTOK * HD / 8 / 256)        // 16384
#define NB_W3 (3 * ID * HD / 8 / 256)      // 2304
#define NB_CW (NTOK / 256)                 // 64

__global__ __launch_bounds__(256) void prep_kernel(
    const float* __restrict__ hs,
    const float* __restrict__ g,
    const float* __restrict__ u,
    const float* __restrict__ d,
    const int* __restrict__ mask,
    const float* __restrict__ rw,
    unsigned short* __restrict__ hs_b,
    unsigned short* __restrict__ wcat_b,
    float* __restrict__ wtok) {
    const int bid = blockIdx.x, tid = threadIdx.x;
    if (bid < NB_HS) {
        size_t i = (size_t)bid * 256 + tid;
        const float4* s = (const float4*)hs;
        float4 a = s[2 * i], b = s[2 * i + 1];
        ushort8 o;
        o[0] = f32_to_bf16_rne(a.x); o[1] = f32_to_bf16_rne(a.y);
        o[2] = f32_to_bf16_rne(a.z); o[3] = f32_to_bf16_rne(a.w);
        o[4] = f32_to_bf16_rne(b.x); o[5] = f32_to_bf16_rne(b.y);
        o[6] = f32_to_bf16_rne(b.z); o[7] = f32_to_bf16_rne(b.w);
        *(ushort8*)(hs_b + 8 * i) = o;
    } else if (bid < NB_HS + NB_W3) {
        int i = (bid - NB_HS) * 256 + tid;
        size_t e = (size_t)i * 8;
        const float* src;
        if (e < (size_t)2 * ID * HD) {
            int rd = (int)(e / HD);
            int c  = (int)(e - (size_t)rd * HD);
            int b = rd >> 4, h = (rd >> 3) & 1, sub = rd & 7;
            src = (h ? u : g) + (size_t)(b * 8 + sub) * HD + c;
        } else {
            src = d + (e - (size_t)2 * ID * HD);
        }
        const float4* s = (const float4*)src;
        float4 a = s[0], bq = s[1];
        ushort8 o;
        o[0] = f32_to_bf16_rne(a.x);  o[1] = f32_to_bf16_rne(a.y);
        o[2] = f32_to_bf16_rne(a.z);  o[3] = f32_to_bf16_rne(a.w);
        o[4] = f32_to_bf16_rne(bq.x); o[5] = f32_to_bf16_rne(bq.y);
        o[6] = f32_to_bf16_rne(bq.z); o[7] = f32_to_bf16_rne(bq.w);
        *(ushort8*)(wcat_b + e) = o;
    } else {
        int k = (bid - NB_HS - NB_W3) * 256 + tid;
        if (k < NTOK) {
            float acc = 0.f;
#pragma unroll
            for (int j = 0; j < TOPK; ++j)
                acc += (float)mask[j * NTOK + k] * rw[k * TOPK + j];
            wtok[k] = acc;
        }
    }
}

// ================= GU GEMM: 256x128 tile, BK=32, 3 blocks/CU ===================
// A[NTOK,HD] bf16, B = interleaved [gate;up] rows [1536,HD] bf16.
// 8 waves 4Mx2N, per-wave 64x64. VGPR 60, LDS 48KB -> 3 blocks/CU fit; grid
// 768 = 256 CU x 3 -> ALL blocks co-resident, zero tail. launch_bounds(512,6)
// declares 6 waves/EU (r11/r12 had (512,4) = 2 blk/CU, capping occupancy).
__global__ __launch_bounds__(512, 6) void gemm_gu_kernel(
    const unsigned short* __restrict__ A,
    const unsigned short* __restrict__ B,
    unsigned short* __restrict__ act) {
    constexpr int K = HD;          // 2048
    constexpr int NT = K / 32;     // 64
    __shared__ __align__(16) unsigned char lds[2][24576];   // A 16K | B 8K

    const int bid = blockIdx.x, nwg = gridDim.x;          // 768
    const int nb = (bid & 7) * (nwg >> 3) + (bid >> 3);   // XCD-chunked
    const int by = nb / 12, bx = nb - by * 12;            // bx fastest: A-panel reuse
    const int row0 = by * 256, col0 = bx * 128;

    const int tid = threadIdx.x, wid = tid >> 6, lane = tid & 63;
    const int wr = wid >> 1, wc = wid & 1;
    const int lrow = lane & 15, q = lane >> 4;
    const int rsw = ((q ^ ((lrow >> 1) & 3)) << 4);       // read-side swizzle (bytes)

    const int kswz = (((lane & 3) ^ ((lane >> 3) & 3)) << 3);   // elems
    const int srow = wid * 16 + (lane >> 2);
    const unsigned short* s0 = A + (size_t)(row0 + srow) * K + kswz;         // A rows 0..127
    const unsigned short* s1 = A + (size_t)(row0 + 128 + srow) * K + kswz;   // A rows 128..255
    const unsigned short* s2 = B + (size_t)(col0 + srow) * K + kswz;         // B rows 0..127

#define STAGE(sb, kt) do {                                                  \
        GLD_LDS(s0 + (kt) * 32, lds[sb] + wid * 1024);                      \
        GLD_LDS(s1 + (kt) * 32, lds[sb] + 8192 + wid * 1024);               \
        GLD_LDS(s2 + (kt) * 32, lds[sb] + 16384 + wid * 1024);              \
    } while (0)

    floatx4 acc[4][4];
#pragma unroll
    for (int m = 0; m < 4; ++m)
#pragma unroll
        for (int n = 0; n < 4; ++n) acc[m][n] = (floatx4){0.f, 0.f, 0.f, 0.f};
    bf16x8 af[4], bb[4];

    STAGE(0, 0);

    for (int t = 0; t < NT; ++t) {
        const int s = t & 1;
        if (t + 1 < NT) {
            STAGE(s ^ 1, t + 1);
            wait_vm<3>();          // forces tile t's 3; t+1's 3 stay in flight
        } else {
            wait_vm<0>();
        }
        BARRIER();
        const unsigned char* la = lds[s];
        const unsigned char* lb = lds[s] + 16384;
#pragma unroll
        for (int m = 0; m < 4; ++m)
            af[m] = *(const bf16x8*)(la + (wr * 64 + m * 16 + lrow) * 64 + rsw);
#pragma unroll
        for (int n = 0; n < 4; ++n)
            bb[n] = *(const bf16x8*)(lb + (wc * 64 + n * 16 + lrow) * 64 + rsw);
        __builtin_amdgcn_s_setprio(1);
#pragma unroll
        for (int m = 0; m < 4; ++m)
#pragma unroll
            for (int n = 0; n < 4; ++n)
                acc[m][n] = __builtin_amdgcn_mfma_f32_16x16x32_bf16(af[m], bb[n], acc[m][n], 0, 0, 0);
        __builtin_amdgcn_s_setprio(0);
        BARRIER();
    }
#undef STAGE

    // Fused SwiGLU epilogue. D frag: col = lane&15, row = q*4 + r.
    // B-rows 8-block interleaved: lanes lrow<8 hold gate_i, lrow>=8 hold up_i
    // (i = ibase + (lrow&7)). shfl_xor(8) pairs them. silu via v_exp + v_rcp.
#pragma unroll
    for (int m = 0; m < 4; ++m) {
        const int rowb = row0 + wr * 64 + m * 16 + q * 4;
        float sv[4][4];
#pragma unroll
        for (int n = 0; n < 4; ++n)
#pragma unroll
            for (int r = 0; r < 4; ++r) {
                const float gf = acc[m][n][r];
                const float uf = __shfl_xor(gf, 8, 64);
                const float sig = __builtin_amdgcn_rcpf(1.f + __expf(-gf));
                sv[n][r] = gf * sig * uf;
            }
        if ((lrow & 8) == 0) {
            const int ib0 = (col0 >> 1) + wc * 32 + (lrow & 7);
#pragma unroll
            for (int n = 0; n < 4; ++n)
#pragma unroll
                for (int r = 0; r < 4; ++r)
                    act[(size_t)(rowb + r) * ID + ib0 + n * 8] = f32_to_bf16_rne(sv[n][r]);
        }
    }
}

// ================= DOWN GEMM: 128x128 tile, 2 blocks/CU (LDS-capped) ===========
__global__ __launch_bounds__(256, 2) void gemm_down_kernel(
    const unsigned short* __restrict__ A,
    const unsigned short* __restrict__ B,
    const float* __restrict__ fin,
    const float* __restrict__ wtok,
    float* __restrict__ out) {
    constexpr int K = ID;          // 768
    constexpr int NT = K / 64;     // 12
    __shared__ __align__(16) unsigned char lds[2][32768];   // A 16K | B 16K

    const int bid = blockIdx.x, nwg = gridDim.x;            // 2048
    const int nb = (bid & 7) * (nwg >> 3) + (bid >> 3);     // XCD-chunked
    const int bx = nb & 15, by = nb >> 4;                   // bx fastest: A-panel reuse
    const int row0 = by * 128, col0 = bx * 128;

    const int tid = threadIdx.x, wid = tid >> 6, lane = tid & 63;
    const int wr = wid >> 1, wc = wid & 1;
    const int lrow = lane & 15, q = lane >> 4;

    const int srow = wid * 8 + (lane >> 3);
    const int sk = (((lane & 7) ^ ((lane >> 3) & 7)) << 3);   // elems
    const unsigned short* sA[4];
    const unsigned short* sB[4];
#pragma unroll
    for (int r = 0; r < 4; ++r) {
        sA[r] = A + (size_t)(row0 + r * 32 + srow) * K + sk;
        sB[r] = B + (size_t)(col0 + r * 32 + srow) * K + sk;
    }

#define STAGE_T(sb, kt) do {                                                    \
        _Pragma("unroll")                                                       \
        for (int r = 0; r < 4; ++r)                                             \
            GLD_LDS(sA[r] + (kt) * 64, lds[sb] + r * 4096 + wid * 1024);        \
        _Pragma("unroll")                                                       \
        for (int r = 0; r < 4; ++r)                                             \
            GLD_LDS(sB[r] + (kt) * 64, lds[sb] + 16384 + r * 4096 + wid * 1024);\
    } while (0)

    floatx4 acc[4][4];
#pragma unroll
    for (int m = 0; m < 4; ++m)
#pragma unroll
        for (int n = 0; n < 4; ++n) acc[m][n] = (floatx4){0.f, 0.f, 0.f, 0.f};
    bf16x8 af[4], bb[4];

    STAGE_T(0, 0);

    for (int t = 0; t < NT; ++t) {
        const int s = t & 1;
        if (t + 1 < NT) {
            STAGE_T(s ^ 1, t + 1);
            wait_vm<8>();          // forces tile t landed; t+1's 8 stay in flight
        } else {
            wait_vm<0>();
        }
        BARRIER();
        const unsigned char* la = lds[s];
        const unsigned char* lb = lds[s] + 16384;
#pragma unroll
        for (int ks = 0; ks < 2; ++ks) {
#pragma unroll
            for (int m = 0; m < 4; ++m)
                af[m] = *(const bf16x8*)(la + (wr * 64 + m * 16 + lrow) * 128 +
                                         (((ks * 4 + q) ^ (lrow & 7)) << 4));
#pragma unroll
            for (int n = 0; n < 4; ++n)
                bb[n] = *(const bf16x8*)(lb + (wc * 64 + n * 16 + lrow) * 128 +
                                         (((ks * 4 + q) ^ (lrow & 7)) << 4));
            __builtin_amdgcn_s_setprio(1);
#pragma unroll
            for (int m = 0; m < 4; ++m)
#pragma unroll
                for (int n = 0; n < 4; ++n)
                    acc[m][n] = __builtin_amdgcn_mfma_f32_16x16x32_bf16(af[m], bb[n], acc[m][n], 0, 0, 0);
            __builtin_amdgcn_s_setprio(0);
        }
        BARRIER();
    }
#undef STAGE_T

#pragma unroll
    for (int m = 0; m < 4; ++m)
#pragma unroll
        for (int r = 0; r < 4; ++r) {
            const int row = row0 + wr * 64 + m * 16 + q * 4 + r;
            const float wv = wtok[row];
#pragma unroll
            for (int n = 0; n < 4; ++n) {
                const int col = col0 + wc * 64 + n * 16 + lrow;
                out[(size_t)row * HD + col] = fin[(size_t)row * HD + col] + wv * acc[m][n][r];
            }
        }
}

extern "C" void kernel_launch(void* const* d_in, const int* in_sizes, int n_in,
                              void* d_out, int out_size, void* d_ws, size_t ws_size,
                              hipStream_t stream) {
    const float* hs   = (const float*)d_in[0];
    const int*   mask = (const int*)d_in[1];
    const float* rw   = (const float*)d_in[2];
    const float* fin  = (const float*)d_in[3];
    const float* gw   = (const float*)d_in[4];
    const float* uw   = (const float*)d_in[5];
    const float* dw   = (const float*)d_in[6];
    float* out = (float*)d_out;

    char* ws = (char*)d_ws;
    unsigned short* hs_b   = (unsigned short*)ws; ws += (size_t)NTOK * HD * 2;
    unsigned short* wcat_b = (unsigned short*)ws; ws += (size_t)3 * ID * HD * 2;  // gu-interleaved | down
    unsigned short* act_b  = (unsigned short*)ws; ws += (size_t)NTOK * ID * 2;
    float* wtok = (float*)ws;
    unsigned short* down_b = wcat_b + (size_t)2 * ID * HD;

    // prep: hs->bf16, weights->bf16 (gu interleaved), w[k] — one dispatch
    prep_kernel<<<NB_HS + NB_W3 + NB_CW, 256, 0, stream>>>(
        hs, gw, uw, dw, mask, rw, hs_b, wcat_b, wtok);

    // GU + fused SwiGLU: act[16384,768] = silu(hs*G^T) * (hs*U^T)
    // 256x128 tiles, grid 768 blocks = 3 blocks/CU, all co-resident
    gemm_gu_kernel<<<768, 512, 0, stream>>>(hs_b, wcat_b, act_b);

    // DOWN: out = fin + w * (act * down^T), 128x128 tiles, 2048 blocks, 2 blk/CU
    gemm_down_kernel<<<2048, 256, 0, stream>>>(act_b, down_b, fin, wtok, out);
}

// Round 14
// 224.332 us; speedup vs baseline: 5.1161x; 5.1161x over previous
//
#include <hip/hip_runtime.h>
#include <stdint.h>

#define NTOK 16384
#define HD   2048
#define ID   768
#define TOPK 8

typedef __bf16 bf16x8 __attribute__((ext_vector_type(8)));
typedef float  floatx4 __attribute__((ext_vector_type(4)));
typedef unsigned short ushort8 __attribute__((ext_vector_type(8)));

__device__ __forceinline__ unsigned short f32_to_bf16_rne(float f) {
    union { float f; uint32_t u; } v; v.f = f;
    uint32_t u = v.u;
    u += 0x7FFFu + ((u >> 16) & 1u);
    return (unsigned short)(u >> 16);
}

// async global->LDS, 16B/lane; LDS dest is wave-uniform base (HW adds lane*16)
#define GLD_LDS(gsrc, ldst)                                                              \
    __builtin_amdgcn_global_load_lds(                                                    \
        (const __attribute__((address_space(1))) uint32_t*)(const void*)(gsrc),          \
        (__attribute__((address_space(3))) uint32_t*)(void*)(ldst), 16, 0, 0)

template<int VM> __device__ __forceinline__ void wait_vm() {
    if constexpr (VM == 8)      asm volatile("s_waitcnt vmcnt(8)" ::: "memory");
    else if constexpr (VM == 4) asm volatile("s_waitcnt vmcnt(4)" ::: "memory");
    else if constexpr (VM == 3) asm volatile("s_waitcnt vmcnt(3)" ::: "memory");
    else                        asm volatile("s_waitcnt vmcnt(0)" ::: "memory");
}
#define BARRIER() do { asm volatile("" ::: "memory");              \
                       __builtin_amdgcn_s_barrier();               \
                       asm volatile("" ::: "memory"); } while (0)

// ---------------- w[k] = sum_j mask[j,k] * rw[k,j] ----------------
__global__ __launch_bounds__(256) void compute_w_kernel(const int* __restrict__ mask,
                                                        const float* __restrict__ rw,
                                                        float* __restrict__ w) {
    int k = blockIdx.x * 256 + threadIdx.x;
    if (k >= NTOK) return;
    float acc = 0.f;
#pragma unroll
    for (int j = 0; j < TOPK; ++j)
        acc += (float)mask[j * NTOK + k] * rw[k * TOPK + j];
    w[k] = acc;
}

// ---------------- fp32 -> bf16 converts ----------------
__global__ __launch_bounds__(256) void convert_hs_kernel(const float* __restrict__ src,
                                                         unsigned short* __restrict__ dst) {
    size_t i = (size_t)blockIdx.x * 256 + threadIdx.x;
    const float4* s = (const float4*)src;
    float4 a = s[2 * i], b = s[2 * i + 1];
    ushort8 o;
    o[0] = f32_to_bf16_rne(a.x); o[1] = f32_to_bf16_rne(a.y);
    o[2] = f32_to_bf16_rne(a.z); o[3] = f32_to_bf16_rne(a.w);
    o[4] = f32_to_bf16_rne(b.x); o[5] = f32_to_bf16_rne(b.y);
    o[6] = f32_to_bf16_rne(b.z); o[7] = f32_to_bf16_rne(b.w);
    *(ushort8*)(dst + 8 * i) = o;
}

// Weights -> bf16 wcat buffer.
// First 2*ID rows (len HD): gate/up 8-row-block interleaved:
//   dst row rd = 16b + 8h + sub  <-  (h ? up : gate) row (8b + sub)
// Then HD rows (len ID) of down, flat.
__global__ __launch_bounds__(256) void convert_w3_kernel(const float* __restrict__ g,
                                                         const float* __restrict__ u,
                                                         const float* __restrict__ d,
                                                         unsigned short* __restrict__ dst) {
    int i = blockIdx.x * 256 + threadIdx.x;          // 8-elem groups
    size_t e = (size_t)i * 8;
    const float* src;
    if (e < (size_t)2 * ID * HD) {
        int rd = (int)(e / HD);
        int c  = (int)(e - (size_t)rd * HD);
        int b = rd >> 4, h = (rd >> 3) & 1, sub = rd & 7;
        src = (h ? u : g) + (size_t)(b * 8 + sub) * HD + c;
    } else {
        src = d + (e - (size_t)2 * ID * HD);
    }
    const float4* s = (const float4*)src;
    float4 a = s[0], bq = s[1];
    ushort8 o;
    o[0] = f32_to_bf16_rne(a.x);  o[1] = f32_to_bf16_rne(a.y);
    o[2] = f32_to_bf16_rne(a.z);  o[3] = f32_to_bf16_rne(a.w);
    o[4] = f32_to_bf16_rne(bq.x); o[5] = f32_to_bf16_rne(bq.y);
    o[6] = f32_to_bf16_rne(bq.z); o[7] = f32_to_bf16_rne(bq.w);
    *(ushort8*)(dst + e) = o;
}

// ================= GU GEMM: 256x192 tile, BK=64, fused SwiGLU epilogue =========
// A[NTOK,HD] bf16, B = interleaved [gate;up] rows [1536,HD] bf16.
// Core loop = the r3-proven variant: staging spread 2/2/2/1 GLD across P0..P3,
// vmcnt(4)@P1 / vmcnt(3)@P3.
// Epilogue: pair gate/up via shfl_xor(8); silu via v_exp + v_rcp (no IEEE div);
// branch hoisted per-m; lanes lrow>=8 compute dead values (never stored).
__global__ __launch_bounds__(512, 1) void gemm_gu_kernel(
    const unsigned short* __restrict__ A,
    const unsigned short* __restrict__ B,
    unsigned short* __restrict__ act) {
    constexpr int K = HD;          // 2048
    constexpr int NT = K / 64;     // 32
    __shared__ __align__(16) unsigned char lds[2][57344];

    const int bid = blockIdx.x, nwg = gridDim.x;          // 512
    const int nb = (bid & 7) * (nwg >> 3) + (bid >> 3);   // XCD-chunked
    const int bx = nb & 7, by = nb >> 3;                  // row-major: A-panel reuse
    const int row0 = by * 256, col0 = bx * 192;

    const int tid = threadIdx.x, wid = tid >> 6, lane = tid & 63;
    const int wr = wid >> 2, wc = wid & 3;
    const int lrow = lane & 15, q = lane >> 4;
    const int rsw = ((q ^ ((lrow >> 1) & 3)) << 4);       // read-side swizzle (bytes)

    const int kswz = (((lane & 3) ^ ((lane >> 3) & 3)) << 3);   // elems
    const unsigned short* sA[2];
#pragma unroll
    for (int h = 0; h < 2; ++h) {
        const int o = h * 8192 + wid * 1024 + lane * 16;
        sA[h] = A + (size_t)(row0 + (o >> 6)) * K + kswz;
    }
    const unsigned short* sB[3];
#pragma unroll
    for (int r = 0; r < 3; ++r) {
        const int o = r * 8192 + tid * 16;
        const int ks = (o >= 12288) ? 1 : 0;
        const int brow = (o - ks * 12288) >> 6;
        sB[r] = B + (size_t)(col0 + brow) * K + ks * 32 + kswz;
    }

#define STAGE_A(sb, ks, kt) do {                                                            \
        GLD_LDS(sA[0] + (kt) * 64 + (ks) * 32, lds[sb] + (ks) * 16384 + wid * 1024);        \
        GLD_LDS(sA[1] + (kt) * 64 + (ks) * 32, lds[sb] + (ks) * 16384 + 8192 + wid * 1024); \
    } while (0)
#define STAGE_B01(sb, kt) do {                                                              \
        GLD_LDS(sB[0] + (kt) * 64, lds[sb] + 32768 + wid * 1024);                           \
        GLD_LDS(sB[1] + (kt) * 64, lds[sb] + 32768 + 8192 + wid * 1024);                    \
    } while (0)
#define STAGE_B2(sb, kt)                                                                    \
        GLD_LDS(sB[2] + (kt) * 64, lds[sb] + 32768 + 16384 + wid * 1024)

#define READ_A(s, ks) do { const unsigned char* rgn = lds[s] + (ks) * 16384;                \
        _Pragma("unroll")                                                                   \
        for (int m = 0; m < 8; ++m)                                                         \
            af[m] = *(const bf16x8*)(rgn + (wr * 128 + m * 16 + lrow) * 64 + rsw);          \
    } while (0)
#define READ_B(s, ks) do { const unsigned char* rgn = lds[s] + 32768 + (ks) * 12288;        \
        _Pragma("unroll")                                                                   \
        for (int n = 0; n < 3; ++n)                                                         \
            bb[n] = *(const bf16x8*)(rgn + (wc * 48 + n * 16 + lrow) * 64 + rsw);           \
    } while (0)
#define MFMA_H(mh) do {                                                                     \
        __builtin_amdgcn_s_setprio(1);                                                      \
        _Pragma("unroll")                                                                   \
        for (int m = (mh) * 4; m < (mh) * 4 + 4; ++m)                                       \
            _Pragma("unroll")                                                               \
            for (int n = 0; n < 3; ++n)                                                     \
                acc[m][n] = __builtin_amdgcn_mfma_f32_16x16x32_bf16(af[m], bb[n], acc[m][n], 0, 0, 0); \
        __builtin_amdgcn_s_setprio(0);                                                      \
    } while (0)

    floatx4 acc[8][3];
#pragma unroll
    for (int m = 0; m < 8; ++m)
#pragma unroll
        for (int n = 0; n < 3; ++n) acc[m][n] = (floatx4){0.f, 0.f, 0.f, 0.f};
    bf16x8 af[8], bb[3];

    // prologue: tile 0 (issue order: A-k0[2], B01[2], A-k1[2], B2[1])
    STAGE_A(0, 0, 0);
    STAGE_B01(0, 0);
    STAGE_A(0, 1, 0);
    STAGE_B2(0, 0);
    wait_vm<3>();          // A-k0 + B01 of tile 0 landed; A-k1,B2 in flight
    BARRIER();

    for (int t = 0; t < NT - 1; ++t) {
        const int s = t & 1, sn = s ^ 1;
        // P0: compute k0/mh0; prefetch A-k0(t+1)
        READ_A(s, 0); READ_B(s, 0);
        STAGE_A(sn, 0, t + 1);
        MFMA_H(0);
        BARRIER();
        // P1: compute k0/mh1; prefetch B01(t+1); land A-k1(t),B2(t)
        STAGE_B01(sn, t + 1);
        MFMA_H(1);
        wait_vm<4>();
        BARRIER();
        // P2: compute k1/mh0; prefetch A-k1(t+1)
        READ_A(s, 1); READ_B(s, 1);
        STAGE_A(sn, 1, t + 1);
        MFMA_H(0);
        BARRIER();
        // P3: compute k1/mh1; prefetch B2(t+1); land A-k0(t+1),B01(t+1)
        STAGE_B2(sn, t + 1);
        MFMA_H(1);
        wait_vm<3>();
        BARRIER();
    }
    {   // peeled final tile
        const int s = (NT - 1) & 1;
        READ_A(s, 0); READ_B(s, 0);
        MFMA_H(0);
        BARRIER();
        MFMA_H(1);
        wait_vm<0>();      // A-k1,B2 of final tile landed
        BARRIER();
        READ_A(s, 1); READ_B(s, 1);
        MFMA_H(0);
        MFMA_H(1);
    }
#undef STAGE_A
#undef STAGE_B01
#undef STAGE_B2
#undef READ_A
#undef READ_B
#undef MFMA_H

    // Fused SwiGLU epilogue. D frag: col = lane&15, row = q*4 + r.
    // B-rows 8-block interleaved: lanes lrow<8 hold gate_i, lrow>=8 hold up_i
    // (i = ibase + (lrow&7)). shfl_xor(8) pairs them. Lanes lrow>=8 compute a
    // dead value and never store. silu via v_exp + v_rcp (bf16-safe).
#pragma unroll
    for (int m = 0; m < 8; ++m) {
        const int rowb = row0 + wr * 128 + m * 16 + q * 4;
        float sv[3][4];
#pragma unroll
        for (int n = 0; n < 3; ++n)
#pragma unroll
            for (int r = 0; r < 4; ++r) {
                const float gf = acc[m][n][r];
                const float uf = __shfl_xor(gf, 8, 64);
                const float sig = __builtin_amdgcn_rcpf(1.f + __expf(-gf));
                sv[n][r] = gf * sig * uf;
            }
        if ((lrow & 8) == 0) {
            const int ib0 = (col0 >> 1) + wc * 24 + lrow;
#pragma unroll
            for (int n = 0; n < 3; ++n)
#pragma unroll
                for (int r = 0; r < 4; ++r)
                    act[(size_t)(rowb + r) * ID + ib0 + n * 8] = f32_to_bf16_rne(sv[n][r]);
        }
    }
}

// ================= DOWN GEMM: 128x128 tile, 2 blocks/CU ========================
__global__ __launch_bounds__(256, 2) void gemm_down_kernel(
    const unsigned short* __restrict__ A,
    const unsigned short* __restrict__ B,
    const float* __restrict__ fin,
    const float* __restrict__ wtok,
    float* __restrict__ out) {
    constexpr int K = ID;          // 768
    constexpr int NT = K / 64;     // 12
    __shared__ __align__(16) unsigned char lds[2][32768];   // A 16K | B 16K

    const int bid = blockIdx.x, nwg = gridDim.x;            // 2048
    const int nb = (bid & 7) * (nwg >> 3) + (bid >> 3);     // XCD-chunked
    const int bx = nb & 15, by = nb >> 4;                   // bx fastest: A-panel reuse
    const int row0 = by * 128, col0 = bx * 128;

    const int tid = threadIdx.x, wid = tid >> 6, lane = tid & 63;
    const int wr = wid >> 1, wc = wid & 1;
    const int lrow = lane & 15, q = lane >> 4;

    const int srow = wid * 8 + (lane >> 3);
    const int sk = (((lane & 7) ^ ((lane >> 3) & 7)) << 3);   // elems
    const unsigned short* sA[4];
    const unsigned short* sB[4];
#pragma unroll
    for (int r = 0; r < 4; ++r) {
        sA[r] = A + (size_t)(row0 + r * 32 + srow) * K + sk;
        sB[r] = B + (size_t)(col0 + r * 32 + srow) * K + sk;
    }

#define STAGE_T(sb, kt) do {                                                    \
        _Pragma("unroll")                                                       \
        for (int r = 0; r < 4; ++r)                                             \
            GLD_LDS(sA[r] + (kt) * 64, lds[sb] + r * 4096 + wid * 1024);        \
        _Pragma("unroll")                                                       \
        for (int r = 0; r < 4; ++r)                                             \
            GLD_LDS(sB[r] + (kt) * 64, lds[sb] + 16384 + r * 4096 + wid * 1024);\
    } while (0)

    floatx4 acc[4][4];
#pragma unroll
    for (int m = 0; m < 4; ++m)
#pragma unroll
        for (int n = 0; n < 4; ++n) acc[m][n] = (floatx4){0.f, 0.f, 0.f, 0.f};
    bf16x8 af[4], bb[4];

    STAGE_T(0, 0);

    for (int t = 0; t < NT; ++t) {
        const int s = t & 1;
        if (t + 1 < NT) {
            STAGE_T(s ^ 1, t + 1);
            wait_vm<8>();          // forces tile t landed; t+1's 8 stay in flight
        } else {
            wait_vm<0>();
        }
        BARRIER();
        const unsigned char* la = lds[s];
        const unsigned char* lb = lds[s] + 16384;
#pragma unroll
        for (int ks = 0; ks < 2; ++ks) {
#pragma unroll
            for (int m = 0; m < 4; ++m)
                af[m] = *(const bf16x8*)(la + (wr * 64 + m * 16 + lrow) * 128 +
                                         (((ks * 4 + q) ^ (lrow & 7)) << 4));
#pragma unroll
            for (int n = 0; n < 4; ++n)
                bb[n] = *(const bf16x8*)(lb + (wc * 64 + n * 16 + lrow) * 128 +
                                         (((ks * 4 + q) ^ (lrow & 7)) << 4));
            __builtin_amdgcn_s_setprio(1);
#pragma unroll
            for (int m = 0; m < 4; ++m)
#pragma unroll
                for (int n = 0; n < 4; ++n)
                    acc[m][n] = __builtin_amdgcn_mfma_f32_16x16x32_bf16(af[m], bb[n], acc[m][n], 0, 0, 0);
            __builtin_amdgcn_s_setprio(0);
        }
        BARRIER();
    }
#undef STAGE_T

#pragma unroll
    for (int m = 0; m < 4; ++m)
#pragma unroll
        for (int r = 0; r < 4; ++r) {
            const int row = row0 + wr * 64 + m * 16 + q * 4 + r;
            const float wv = wtok[row];
#pragma unroll
            for (int n = 0; n < 4; ++n) {
                const int col = col0 + wc * 64 + n * 16 + lrow;
                out[(size_t)row * HD + col] = fin[(size_t)row * HD + col] + wv * acc[m][n][r];
            }
        }
}

extern "C" void kernel_launch(void* const* d_in, const int* in_sizes, int n_in,
                              void* d_out, int out_size, void* d_ws, size_t ws_size,
                              hipStream_t stream) {
    const float* hs   = (const float*)d_in[0];
    const int*   mask = (const int*)d_in[1];
    const float* rw   = (const float*)d_in[2];
    const float* fin  = (const float*)d_in[3];
    const float* gw   = (const float*)d_in[4];
    const float* uw   = (const float*)d_in[5];
    const float* dw   = (const float*)d_in[6];
    float* out = (float*)d_out;

    char* ws = (char*)d_ws;
    unsigned short* hs_b   = (unsigned short*)ws; ws += (size_t)NTOK * HD * 2;
    unsigned short* wcat_b = (unsigned short*)ws; ws += (size_t)3 * ID * HD * 2;  // gu-interleaved | down
    unsigned short* act_b  = (unsigned short*)ws; ws += (size_t)NTOK * ID * 2;
    float* wtok = (float*)ws;
    unsigned short* down_b = wcat_b + (size_t)2 * ID * HD;

    compute_w_kernel<<<NTOK / 256, 256, 0, stream>>>(mask, rw, wtok);
    convert_hs_kernel<<<(NTOK * HD / 8) / 256, 256, 0, stream>>>(hs, hs_b);
    convert_w3_kernel<<<(3 * ID * HD / 8) / 256, 256, 0, stream>>>(gw, uw, dw, wcat_b);

    // GU + fused SwiGLU: act[16384,768] = silu(hs*G^T) * (hs*U^T)
    gemm_gu_kernel<<<512, 512, 0, stream>>>(hs_b, wcat_b, act_b);

    // DOWN: out = fin + w * (act * down^T), 128x128 tiles, 2048 blocks, 2 blk/CU
    gemm_down_kernel<<<2048, 256, 0, stream>>>(act_b, down_b, fin, wtok, out);
}